// Round 6
// baseline (175.473 us; speedup 1.0000x reference)
//
#include <hip/hip_runtime.h>
#include <hip/hip_bf16.h>
#include <math.h>

#define LATENT 256
#define HIDDEN 512
#define NFD    64
#define MAXN   50
#define BATCH  128
#define NPAIR  2450   // 50*49
#define PTILE  128
#define NTILES 20     // ceil(2450/128)

typedef __attribute__((ext_vector_type(8))) short bf16x8;
typedef __attribute__((ext_vector_type(4))) float f32x4;
typedef __attribute__((ext_vector_type(4))) unsigned int u32x4;

__device__ __forceinline__ float sigmoidf_(float x) {
    return 1.0f / (1.0f + expf(-x));
}
__device__ __forceinline__ unsigned short f2b(float f) {   // fp32 -> bf16 RNE
    unsigned u = __builtin_bit_cast(unsigned, f);
    u += 0x7FFFu + ((u >> 16) & 1u);
    return (unsigned short)(u >> 16);
}
__device__ __forceinline__ float b2f(short s) {
    unsigned u = ((unsigned)(unsigned short)s) << 16;
    return __builtin_bit_cast(float, u);
}
__device__ __forceinline__ unsigned cvt_pk_bf16(float lo, float hi) {
    unsigned r;
    asm("v_cvt_pk_bf16_f32 %0, %1, %2" : "=v"(r) : "v"(lo), "v"(hi));
    return r;
}
// e1 8-elem build: relu(b2f(ui)+b2f(uj)) packed to 4x u32 (8 bf16)
__device__ __forceinline__ u32x4 build_e1(bf16x8 ui, bf16x8 uj) {
    u32x4 o;
    #pragma unroll
    for (int t = 0; t < 4; ++t) {
        float lo = fmaxf(b2f(ui[2 * t])     + b2f(uj[2 * t]),     0.f);
        float hh = fmaxf(b2f(ui[2 * t + 1]) + b2f(uj[2 * t + 1]), 0.f);
        o[t] = cvt_pk_bf16(lo, hh);
    }
    return o;
}
// async global(16B/lane) -> LDS (wave-uniform base + lane*16)
__device__ __forceinline__ void gll16(const void* g, void* l) {
    __builtin_amdgcn_global_load_lds(
        (const __attribute__((address_space(1))) void*)g,
        (__attribute__((address_space(3))) void*)l, 16, 0, 0);
}

// ---------------------------------------------------------------------------
// Prologue A (two roles by blockIdx.x):
//  x < 16 : h1 = relu(z@W1^T+b1)  (n0<512)  /  Abc = z@E1z^T+c1 (n0>=512)
//  x >= 16: E2 [256,512] f32 -> E2t chunk-major bf16
// ---------------------------------------------------------------------------
__global__ __launch_bounds__(256) void prologue_a(
    const float* __restrict__ z,
    const float* __restrict__ W1, const float* __restrict__ b1,
    const float* __restrict__ E1, const float* __restrict__ c1,
    const float* __restrict__ E2, unsigned short* __restrict__ E2t,
    float* __restrict__ h1, float* __restrict__ Abc)
{
    const int tid = threadIdx.x;

    if (blockIdx.x >= 16) {   // E2 -> chunk-major bf16
        int idx = ((blockIdx.x - 16) + blockIdx.y * 32) * 256 + tid;  // 16384
        int g  = idx & 255;
        int kc = idx >> 8;
        float4 a = *(const float4*)&E2[(size_t)g * 512 + kc * 8];
        float4 b = *(const float4*)&E2[(size_t)g * 512 + kc * 8 + 4];
        u32x4 o;
        o[0] = (unsigned)f2b(a.x) | ((unsigned)f2b(a.y) << 16);
        o[1] = (unsigned)f2b(a.z) | ((unsigned)f2b(a.w) << 16);
        o[2] = (unsigned)f2b(b.x) | ((unsigned)f2b(b.y) << 16);
        o[3] = (unsigned)f2b(b.z) | ((unsigned)f2b(b.w) << 16);
        *(u32x4*)(E2t + (size_t)idx * 8) = o;
        return;
    }

    __shared__ __align__(16) float As[16][68];
    __shared__ __align__(16) float Bs[16][68];

    const int m0 = blockIdx.y * 64;
    const int n0 = blockIdx.x * 64;          // 0..1023
    const bool isE = n0 >= 512;
    const float* Bp = isE ? E1 + (size_t)(n0 - 512) * 384 : W1 + (size_t)n0 * 256;
    const int ldb = isE ? 384 : 256;

    const int sr = tid >> 2;
    const int kc = (tid & 3) * 4;
    const int tx = tid & 15;
    const int ty = tid >> 4;

    float acc[4][4] = {};

    for (int k0 = 0; k0 < 256; k0 += 16) {
        float4 a4 = *(const float4*)&z[(size_t)(m0 + sr) * 256 + k0 + kc];
        As[kc + 0][sr] = a4.x; As[kc + 1][sr] = a4.y;
        As[kc + 2][sr] = a4.z; As[kc + 3][sr] = a4.w;
        float4 b4 = *(const float4*)&Bp[(size_t)sr * ldb + k0 + kc];
        Bs[kc + 0][sr] = b4.x; Bs[kc + 1][sr] = b4.y;
        Bs[kc + 2][sr] = b4.z; Bs[kc + 3][sr] = b4.w;
        __syncthreads();
        #pragma unroll
        for (int k = 0; k < 16; ++k) {
            float av[4], bv[4];
            *(float4*)av = *(const float4*)&As[k][ty * 4];
            *(float4*)bv = *(const float4*)&Bs[k][tx * 4];
            #pragma unroll
            for (int r = 0; r < 4; ++r)
                #pragma unroll
                for (int c = 0; c < 4; ++c)
                    acc[r][c] = fmaf(av[r], bv[c], acc[r][c]);
        }
        __syncthreads();
    }

    #pragma unroll
    for (int r = 0; r < 4; ++r) {
        int gm = m0 + ty * 4 + r;
        #pragma unroll
        for (int c = 0; c < 4; ++c) {
            int gn = n0 + tx * 4 + c;
            if (isE) {
                int gl = gn - 512;
                Abc[(size_t)gm * 512 + gl] = acc[r][c] + c1[gl];
            } else {
                h1[(size_t)gm * 512 + gn] = fmaxf(acc[r][c] + b1[gn], 0.f);
            }
        }
    }
}

// ---------------------------------------------------------------------------
// fp32 NT gemm, tile 32x64, 256 thr, 2x4/thread.
// EPI: 1 relu->C ; 2 raw->C + sigmoid->C2.  M%32==0, N%64==0, K%16==0.
// ---------------------------------------------------------------------------
template <int EPI>
__global__ __launch_bounds__(256) void gemm_nt32(
    const float* __restrict__ A, int lda,
    const float* __restrict__ B, int ldb,
    const float* __restrict__ bias,
    float* __restrict__ C, int ldc,
    float* __restrict__ C2,
    int K)
{
    __shared__ __align__(16) float As[16][34];
    __shared__ __align__(16) float Bs[16][68];

    const int tid = threadIdx.x;
    const int m0 = blockIdx.y * 32;
    const int n0 = blockIdx.x * 64;
    const int sra = tid >> 3;        // 0..31
    const int kca = (tid & 7) * 2;
    const int srb = tid >> 2;        // 0..63
    const int kcb = (tid & 3) * 4;
    const int tx = tid & 15;
    const int ty = tid >> 4;         // 0..15

    float acc[2][4] = {};

    for (int k0 = 0; k0 < K; k0 += 16) {
        float2 a2 = *(const float2*)&A[(size_t)(m0 + sra) * lda + k0 + kca];
        As[kca][sra] = a2.x; As[kca + 1][sra] = a2.y;
        float4 b4 = *(const float4*)&B[(size_t)(n0 + srb) * ldb + k0 + kcb];
        Bs[kcb + 0][srb] = b4.x; Bs[kcb + 1][srb] = b4.y;
        Bs[kcb + 2][srb] = b4.z; Bs[kcb + 3][srb] = b4.w;
        __syncthreads();
        #pragma unroll
        for (int k = 0; k < 16; ++k) {
            float av[2], bv[4];
            av[0] = As[k][ty * 2]; av[1] = As[k][ty * 2 + 1];
            *(float4*)bv = *(const float4*)&Bs[k][tx * 4];
            #pragma unroll
            for (int r = 0; r < 2; ++r)
                #pragma unroll
                for (int c = 0; c < 4; ++c)
                    acc[r][c] = fmaf(av[r], bv[c], acc[r][c]);
        }
        __syncthreads();
    }

    #pragma unroll
    for (int r = 0; r < 2; ++r) {
        int gm = m0 + ty * 2 + r;
        #pragma unroll
        for (int c = 0; c < 4; ++c) {
            int gn = n0 + tx * 4 + c;
            float v = acc[r][c] + bias[gn];
            if (EPI == 1) v = fmaxf(v, 0.f);
            C[(size_t)gm * ldc + gn] = v;
            if (EPI == 2) C2[(size_t)gm * ldc + gn] = sigmoidf_(v);
        }
    }
}

// ---------------------------------------------------------------------------
// Fused Ui/Uj gemm.  A = nf [6400,64].
// n0<512:  Uib = bf16(nf@E1i^T + Abc[row/50]) ; n0>=512: Ujb = bf16(nf@E1j^T)
// ---------------------------------------------------------------------------
__global__ __launch_bounds__(256) void uiuj_gemm(
    const float* __restrict__ nf,
    const float* __restrict__ E1,
    const float* __restrict__ Abc,
    unsigned short* __restrict__ Uib,
    unsigned short* __restrict__ Ujb)
{
    __shared__ __align__(16) float As[16][68];
    __shared__ __align__(16) float Bs[16][68];

    const int tid = threadIdx.x;
    const int m0 = blockIdx.y * 64;
    const int n0 = blockIdx.x * 64;          // 0..1023
    const bool isJ = n0 >= 512;
    const int nb = n0 & 511;
    const float* Bp = E1 + (size_t)nb * 384 + (isJ ? 320 : 256);

    const int sr = tid >> 2;
    const int kc = (tid & 3) * 4;
    const int tx = tid & 15;
    const int ty = tid >> 4;

    float acc[4][4] = {};

    for (int k0 = 0; k0 < 64; k0 += 16) {
        float4 a4 = *(const float4*)&nf[(size_t)(m0 + sr) * 64 + k0 + kc];
        As[kc + 0][sr] = a4.x; As[kc + 1][sr] = a4.y;
        As[kc + 2][sr] = a4.z; As[kc + 3][sr] = a4.w;
        float4 b4 = *(const float4*)&Bp[(size_t)sr * 384 + k0 + kc];
        Bs[kc + 0][sr] = b4.x; Bs[kc + 1][sr] = b4.y;
        Bs[kc + 2][sr] = b4.z; Bs[kc + 3][sr] = b4.w;
        __syncthreads();
        #pragma unroll
        for (int k = 0; k < 16; ++k) {
            float av[4], bv[4];
            *(float4*)av = *(const float4*)&As[k][ty * 4];
            *(float4*)bv = *(const float4*)&Bs[k][tx * 4];
            #pragma unroll
            for (int r = 0; r < 4; ++r)
                #pragma unroll
                for (int c = 0; c < 4; ++c)
                    acc[r][c] = fmaf(av[r], bv[c], acc[r][c]);
        }
        __syncthreads();
    }

    unsigned short* dst = isJ ? Ujb : Uib;
    #pragma unroll
    for (int r = 0; r < 4; ++r) {
        int gm = m0 + ty * 4 + r;
        int bidx = gm / 50;
        #pragma unroll
        for (int c = 0; c < 4; ++c) {
            int gl = nb + tx * 4 + c;
            float v = acc[r][c];
            if (!isJ) v += Abc[(size_t)bidx * 512 + gl];
            dst[(size_t)gm * 512 + gl] = f2b(v);
        }
    }
}

// ---------------------------------------------------------------------------
// MFMA edge kernel v5: fat waves to unload the LDS pipe.
//  Block: 256 thr = 4 waves (wr=wid>>1, wc=wid&1), block tile 128x256,
//  wave tile 64(M) x 128(N), acc[4][8].
//  Per CU-kstep (2 blocks): LDS = 8 waves x (4 af + 8 bf + 2 wr) x 12 cyc
//  = 1344 cyc ~ balanced with MFMA 1242 cyc (was 1728 vs 1242).
//  A (e1): XOR-swizzled LDS, double-buffered, built in-regs from Ui/Uj.
//  B (E2t): gll -> triple-buffered LDS, prefetch distance 2, counted vmcnt.
// ---------------------------------------------------------------------------
__global__ __launch_bounds__(256, 2) void edge_mfma(
    const unsigned short* __restrict__ Ui,   // [B,50,512] bf16 (incl. Abc+c1)
    const unsigned short* __restrict__ Uj,   // [B,50,512] bf16
    const unsigned short* __restrict__ E2t,  // [64 kc][256 g][8] bf16
    const float* __restrict__ c2,
    const float* __restrict__ E3,
    const float* __restrict__ c3p,
    float* __restrict__ outE)                // [B,2450]
{
    __shared__ unsigned short As[2][PTILE * 32];   // 16KB, swizzled
    __shared__ unsigned short Bs[3][8192];         // 48KB, linear chunk-major
    __shared__ float c2_s[256], e3_s[256];
    __shared__ int   ii_s[PTILE], jj_s[PTILE];
    __shared__ float red[PTILE][3];

    const int b   = blockIdx.y;
    const int p0  = blockIdx.x * PTILE;
    const int tid = threadIdx.x;
    const int lane = tid & 63;
    const int wid  = tid >> 6;    // 0..3
    const int wr = wid >> 1;      // 0..1 : M half
    const int wc = wid & 1;       // 0..1 : N half
    const int ln = lane & 15;
    const int hi = lane >> 4;

    c2_s[tid] = c2[tid];
    e3_s[tid] = E3[tid];
    if (tid < PTILE) {
        int p = p0 + tid;
        int i = 0, j = 0;
        if (p < NPAIR) {
            i = p / 49;
            int kk = p - i * 49;
            j = kk + (kk >= i ? 1 : 0);
        }
        ii_s[tid] = i;
        jj_s[tid] = j;
    }
    __syncthreads();

    const unsigned short* UiB = Ui + (size_t)b * MAXN * HIDDEN;
    const unsigned short* UjB = Uj + (size_t)b * MAXN * HIDDEN;

    // A staging: thread -> row (tid>>1), chunks 2*(tid&1), 2*(tid&1)+1
    const int srow = tid >> 1;
    const int cb   = (tid & 1) * 2;
    const unsigned short* gUi = UiB + (size_t)ii_s[srow] * HIDDEN + cb * 8;
    const unsigned short* gUj = UjB + (size_t)jj_s[srow] * HIDDEN + cb * 8;
    const int sw0 = srow * 32 + (((cb    ) ^ ((srow >> 1) & 3)) * 8);
    const int sw1 = srow * 32 + (((cb + 1) ^ ((srow >> 1) & 3)) * 8);

    // A fragment read address (swizzled); af[mi] at ard + mi*512
    const int arow = 64 * wr + ln;
    const int q    = hi ^ ((ln >> 1) & 3);
    const int ard  = arow * 32 + q * 8;

    // B: per-wave gll src/dst; fragment read addr brd + ni*128
    const unsigned short* gB = E2t + wid * 2048 + lane * 8;  // + ks*8192 + s*512
    const int bdst = wid * 2048;                             // + s*512
    const int brd  = hi * 2048 + (128 * wc + ln) * 8;

    f32x4 acc[4][8] = {};

    // ---- prologue: A(0)->LDS; gll B(0)->Bs[0], B(1)->Bs[1]; U(1) regs
    {
        bf16x8 u0 = *(const bf16x8*)gUi;
        bf16x8 u1 = *(const bf16x8*)(gUi + 8);
        bf16x8 v0 = *(const bf16x8*)gUj;
        bf16x8 v1 = *(const bf16x8*)(gUj + 8);
        *(u32x4*)&As[0][sw0] = build_e1(u0, v0);
        *(u32x4*)&As[0][sw1] = build_e1(u1, v1);
    }
    #pragma unroll
    for (int s = 0; s < 4; ++s) {
        gll16(gB + s * 512,        &Bs[0][bdst + s * 512]);
        gll16(gB + 8192 + s * 512, &Bs[1][bdst + s * 512]);
    }
    bf16x8 uiN0 = *(const bf16x8*)(gUi + 32);
    bf16x8 uiN1 = *(const bf16x8*)(gUi + 40);
    bf16x8 ujN0 = *(const bf16x8*)(gUj + 32);
    bf16x8 ujN1 = *(const bf16x8*)(gUj + 40);
    // drain B(0) (4 oldest gll); keep B(1) gll x4 + U(1) x4 in flight
    asm volatile("s_waitcnt vmcnt(8) lgkmcnt(0)\n\ts_barrier" ::: "memory");

    #pragma unroll
    for (int ks = 0; ks < 16; ++ks) {
        const int ab = ks & 1;        // A buffer
        const int bb = ks % 3;        // B buffer
        // issue gll B(ks+2) -> Bs[(ks+2)%3] (last read at iter ks-1)
        if (ks < 14) {
            const int bn = (ks + 2) % 3;
            const unsigned short* src = gB + (size_t)(ks + 2) * 8192;
            #pragma unroll
            for (int s = 0; s < 4; ++s)
                gll16(src + s * 512, &Bs[bn][bdst + s * 512]);
        }
        // build + store A(ks+1) (consumes U(ks+1) loaded at iter ks-1)
        if (ks < 15) {
            *(u32x4*)&As[ab ^ 1][sw0] = build_e1(uiN0, ujN0);
            *(u32x4*)&As[ab ^ 1][sw1] = build_e1(uiN1, ujN1);
        }
        // prefetch U(ks+2) registers
        if (ks < 14) {
            uiN0 = *(const bf16x8*)(gUi + 32 * (ks + 2));
            uiN1 = *(const bf16x8*)(gUi + 32 * (ks + 2) + 8);
            ujN0 = *(const bf16x8*)(gUj + 32 * (ks + 2));
            ujN1 = *(const bf16x8*)(gUj + 32 * (ks + 2) + 8);
        }

        bf16x8 af[4], bf[8];
        #pragma unroll
        for (int mi = 0; mi < 4; ++mi)
            af[mi] = *(const bf16x8*)&As[ab][ard + mi * 512];
        #pragma unroll
        for (int ni = 0; ni < 8; ++ni)
            bf[ni] = *(const bf16x8*)&Bs[bb][brd + ni * 128];

        __builtin_amdgcn_s_setprio(1);
        #pragma unroll
        for (int ni = 0; ni < 8; ++ni)
            #pragma unroll
            for (int mi = 0; mi < 4; ++mi)
                acc[mi][ni] = __builtin_amdgcn_mfma_f32_16x16x32_bf16(
                    af[mi], bf[ni], acc[mi][ni], 0, 0, 0);
        __builtin_amdgcn_s_setprio(0);

        // counted barrier: keep the 8 newest (gll B(ks+2) x4 + U(ks+2) x4)
        // in flight; B(ks+1) (a full iter old) is complete/drained.
        if (ks < 14) {
            asm volatile("s_waitcnt vmcnt(8) lgkmcnt(0)\n\ts_barrier" ::: "memory");
        } else if (ks == 14) {
            asm volatile("s_waitcnt vmcnt(0) lgkmcnt(0)\n\ts_barrier" ::: "memory");
        }
        // ks == 15: no barrier; epilogue touches only regs + `red`
    }

    // ---- epilogue: relu(+c2), dot E3, 16-lane shuffle reduce, cross-wave LDS
    const float c3v = c3p[0];
    #pragma unroll
    for (int mi = 0; mi < 4; ++mi) {
        #pragma unroll
        for (int r = 0; r < 4; ++r) {
            float part = 0.f;
            #pragma unroll
            for (int ni = 0; ni < 8; ++ni) {
                int g = 128 * wc + 16 * ni + ln;
                float v = fmaxf(acc[mi][ni][r] + c2_s[g], 0.f);
                part = fmaf(v, e3_s[g], part);
            }
            part += __shfl_xor(part, 1);
            part += __shfl_xor(part, 2);
            part += __shfl_xor(part, 4);
            part += __shfl_xor(part, 8);
            if (ln == 0) red[64 * wr + 16 * mi + 4 * hi + r][wc] = part;
        }
    }
    __syncthreads();

    if (tid < PTILE) {
        int p = p0 + tid;
        if (p < NPAIR) {
            float s = red[tid][0] + red[tid][1] + c3v;
            outE[(size_t)b * NPAIR + p] = sigmoidf_(s);
        }
    }
}

// ---------------------------------------------------------------------------
extern "C" void kernel_launch(void* const* d_in, const int* in_sizes, int n_in,
                              void* d_out, int out_size, void* d_ws, size_t ws_size,
                              hipStream_t stream)
{
    const float* z  = (const float*)d_in[0];
    const float* W1 = (const float*)d_in[1];
    const float* b1 = (const float*)d_in[2];
    const float* W2 = (const float*)d_in[3];
    const float* b2 = (const float*)d_in[4];
    const float* W3 = (const float*)d_in[5];
    const float* b3 = (const float*)d_in[6];
    const float* E1 = (const float*)d_in[7];
    const float* c1 = (const float*)d_in[8];
    const float* E2 = (const float*)d_in[9];
    const float* c2 = (const float*)d_in[10];
    const float* E3 = (const float*)d_in[11];
    const float* c3 = (const float*)d_in[12];

    float* out = (float*)d_out;
    float* ws  = (float*)d_ws;

    // workspace layout
    float* h1  = ws;                        // 128*512 f32
    float* h2  = h1 + 65536;                // 128*512 f32
    float* nf  = h2 + 65536;                // 128*3200 f32
    float* Abc = nf + 409600;               // 128*512 f32
    unsigned short* Uib = (unsigned short*)(Abc + 65536);   // 128*50*512 bf16
    unsigned short* Ujb = Uib + (size_t)BATCH * MAXN * 512; // 128*50*512 bf16
    unsigned short* E2t = Ujb + (size_t)BATCH * MAXN * 512; // 64*256*8 bf16

    dim3 blk(256);

    // h1, Abc, E2t
    prologue_a<<<dim3(48, 2), blk, 0, stream>>>(z, W1, b1, E1, c1, E2, E2t, h1, Abc);

    // h2 = relu(h1@W2^T+b2)   (32 blocks)
    gemm_nt32<1><<<dim3(8, 4), blk, 0, stream>>>(
        h1, HIDDEN, W2, HIDDEN, b2, h2, HIDDEN, nullptr, HIDDEN);

    // nf raw -> ws ; sigmoid(nf) -> out   (200 blocks)
    gemm_nt32<2><<<dim3(50, 4), blk, 0, stream>>>(
        h2, HIDDEN, W3, HIDDEN, b3, nf, 3200, out, HIDDEN);

    // Ui' = bf16(nf@E1i^T + Abc) ; Uj = bf16(nf@E1j^T)
    uiuj_gemm<<<dim3(16, 100), blk, 0, stream>>>(nf, E1, Abc, Uib, Ujb);

    // fused edge MLP with MFMA
    edge_mfma<<<dim3(NTILES, BATCH), blk, 0, stream>>>(
        Uib, Ujb, E2t, c2, E3, c3, out + BATCH * MAXN * NFD);
}

// Round 7
// 165.545 us; speedup vs baseline: 1.0600x; 1.0600x over previous
//
#include <hip/hip_runtime.h>
#include <hip/hip_bf16.h>
#include <math.h>

#define LATENT 256
#define HIDDEN 512
#define NFD    64
#define MAXN   50
#define BATCH  128
#define NPAIR  2450   // 50*49
#define PTILE  128
#define NTILES 20     // ceil(2450/128)

typedef __attribute__((ext_vector_type(8))) _Float16 f16x8;
typedef __attribute__((ext_vector_type(4))) float f32x4;
typedef __attribute__((ext_vector_type(4))) unsigned int u32x4;

__device__ __forceinline__ float sigmoidf_(float x) {
    return 1.0f / (1.0f + expf(-x));
}
// e1 8-elem build in fp16: relu(ui+uj) -> 4x v_pk_add_f16 + 4x v_pk_max_f16
__device__ __forceinline__ u32x4 build_e1(f16x8 ui, f16x8 uj) {
    f16x8 s = ui + uj;
    f16x8 m = __builtin_elementwise_max(s, (f16x8)(_Float16)0);
    return __builtin_bit_cast(u32x4, m);
}
// async global(16B/lane) -> LDS (wave-uniform base + lane*16)
__device__ __forceinline__ void gll16(const void* g, void* l) {
    __builtin_amdgcn_global_load_lds(
        (const __attribute__((address_space(1))) void*)g,
        (__attribute__((address_space(3))) void*)l, 16, 0, 0);
}

// ---------------------------------------------------------------------------
// Prologue A (two roles by blockIdx.x):
//  x < 16 : h1 = relu(z@W1^T+b1)  (n0<512)  /  Abc = z@E1z^T+c1 (n0>=512)
//  x >= 16: E2 [256,512] f32 -> E2t chunk-major fp16
// ---------------------------------------------------------------------------
__global__ __launch_bounds__(256) void prologue_a(
    const float* __restrict__ z,
    const float* __restrict__ W1, const float* __restrict__ b1,
    const float* __restrict__ E1, const float* __restrict__ c1,
    const float* __restrict__ E2, unsigned short* __restrict__ E2t,
    float* __restrict__ h1, float* __restrict__ Abc)
{
    const int tid = threadIdx.x;

    if (blockIdx.x >= 16) {   // E2 -> chunk-major fp16
        int idx = ((blockIdx.x - 16) + blockIdx.y * 32) * 256 + tid;  // 16384
        int g  = idx & 255;
        int kc = idx >> 8;
        float4 a = *(const float4*)&E2[(size_t)g * 512 + kc * 8];
        float4 b = *(const float4*)&E2[(size_t)g * 512 + kc * 8 + 4];
        f16x8 h;
        h[0] = (_Float16)a.x; h[1] = (_Float16)a.y;
        h[2] = (_Float16)a.z; h[3] = (_Float16)a.w;
        h[4] = (_Float16)b.x; h[5] = (_Float16)b.y;
        h[6] = (_Float16)b.z; h[7] = (_Float16)b.w;
        *(u32x4*)(E2t + (size_t)idx * 8) = __builtin_bit_cast(u32x4, h);
        return;
    }

    __shared__ __align__(16) float As[16][68];
    __shared__ __align__(16) float Bs[16][68];

    const int m0 = blockIdx.y * 64;
    const int n0 = blockIdx.x * 64;          // 0..1023
    const bool isE = n0 >= 512;
    const float* Bp = isE ? E1 + (size_t)(n0 - 512) * 384 : W1 + (size_t)n0 * 256;
    const int ldb = isE ? 384 : 256;

    const int sr = tid >> 2;
    const int kc = (tid & 3) * 4;
    const int tx = tid & 15;
    const int ty = tid >> 4;

    float acc[4][4] = {};

    for (int k0 = 0; k0 < 256; k0 += 16) {
        float4 a4 = *(const float4*)&z[(size_t)(m0 + sr) * 256 + k0 + kc];
        As[kc + 0][sr] = a4.x; As[kc + 1][sr] = a4.y;
        As[kc + 2][sr] = a4.z; As[kc + 3][sr] = a4.w;
        float4 b4 = *(const float4*)&Bp[(size_t)sr * ldb + k0 + kc];
        Bs[kc + 0][sr] = b4.x; Bs[kc + 1][sr] = b4.y;
        Bs[kc + 2][sr] = b4.z; Bs[kc + 3][sr] = b4.w;
        __syncthreads();
        #pragma unroll
        for (int k = 0; k < 16; ++k) {
            float av[4], bv[4];
            *(float4*)av = *(const float4*)&As[k][ty * 4];
            *(float4*)bv = *(const float4*)&Bs[k][tx * 4];
            #pragma unroll
            for (int r = 0; r < 4; ++r)
                #pragma unroll
                for (int c = 0; c < 4; ++c)
                    acc[r][c] = fmaf(av[r], bv[c], acc[r][c]);
        }
        __syncthreads();
    }

    #pragma unroll
    for (int r = 0; r < 4; ++r) {
        int gm = m0 + ty * 4 + r;
        #pragma unroll
        for (int c = 0; c < 4; ++c) {
            int gn = n0 + tx * 4 + c;
            if (isE) {
                int gl = gn - 512;
                Abc[(size_t)gm * 512 + gl] = acc[r][c] + c1[gl];
            } else {
                h1[(size_t)gm * 512 + gn] = fmaxf(acc[r][c] + b1[gn], 0.f);
            }
        }
    }
}

// ---------------------------------------------------------------------------
// fp32 NT gemm, tile 32x64, 256 thr, 2x4/thread.
// EPI: 1 relu->C ; 2 raw->C + sigmoid->C2.  M%32==0, N%64==0, K%16==0.
// ---------------------------------------------------------------------------
template <int EPI>
__global__ __launch_bounds__(256) void gemm_nt32(
    const float* __restrict__ A, int lda,
    const float* __restrict__ B, int ldb,
    const float* __restrict__ bias,
    float* __restrict__ C, int ldc,
    float* __restrict__ C2,
    int K)
{
    __shared__ __align__(16) float As[16][34];
    __shared__ __align__(16) float Bs[16][68];

    const int tid = threadIdx.x;
    const int m0 = blockIdx.y * 32;
    const int n0 = blockIdx.x * 64;
    const int sra = tid >> 3;        // 0..31
    const int kca = (tid & 7) * 2;
    const int srb = tid >> 2;        // 0..63
    const int kcb = (tid & 3) * 4;
    const int tx = tid & 15;
    const int ty = tid >> 4;         // 0..15

    float acc[2][4] = {};

    for (int k0 = 0; k0 < K; k0 += 16) {
        float2 a2 = *(const float2*)&A[(size_t)(m0 + sra) * lda + k0 + kca];
        As[kca][sra] = a2.x; As[kca + 1][sra] = a2.y;
        float4 b4 = *(const float4*)&B[(size_t)(n0 + srb) * ldb + k0 + kcb];
        Bs[kcb + 0][srb] = b4.x; Bs[kcb + 1][srb] = b4.y;
        Bs[kcb + 2][srb] = b4.z; Bs[kcb + 3][srb] = b4.w;
        __syncthreads();
        #pragma unroll
        for (int k = 0; k < 16; ++k) {
            float av[2], bv[4];
            av[0] = As[k][ty * 2]; av[1] = As[k][ty * 2 + 1];
            *(float4*)bv = *(const float4*)&Bs[k][tx * 4];
            #pragma unroll
            for (int r = 0; r < 2; ++r)
                #pragma unroll
                for (int c = 0; c < 4; ++c)
                    acc[r][c] = fmaf(av[r], bv[c], acc[r][c]);
        }
        __syncthreads();
    }

    #pragma unroll
    for (int r = 0; r < 2; ++r) {
        int gm = m0 + ty * 2 + r;
        #pragma unroll
        for (int c = 0; c < 4; ++c) {
            int gn = n0 + tx * 4 + c;
            float v = acc[r][c] + bias[gn];
            if (EPI == 1) v = fmaxf(v, 0.f);
            C[(size_t)gm * ldc + gn] = v;
            if (EPI == 2) C2[(size_t)gm * ldc + gn] = sigmoidf_(v);
        }
    }
}

// ---------------------------------------------------------------------------
// Fused Ui/Uj gemm.  A = nf [6400,64].  Output fp16.
// n0<512:  Uih = f16(nf@E1i^T + Abc[row/50]) ; n0>=512: Ujh = f16(nf@E1j^T)
// ---------------------------------------------------------------------------
__global__ __launch_bounds__(256) void uiuj_gemm(
    const float* __restrict__ nf,
    const float* __restrict__ E1,
    const float* __restrict__ Abc,
    unsigned short* __restrict__ Uih,
    unsigned short* __restrict__ Ujh)
{
    __shared__ __align__(16) float As[16][68];
    __shared__ __align__(16) float Bs[16][68];

    const int tid = threadIdx.x;
    const int m0 = blockIdx.y * 64;
    const int n0 = blockIdx.x * 64;          // 0..1023
    const bool isJ = n0 >= 512;
    const int nb = n0 & 511;
    const float* Bp = E1 + (size_t)nb * 384 + (isJ ? 320 : 256);

    const int sr = tid >> 2;
    const int kc = (tid & 3) * 4;
    const int tx = tid & 15;
    const int ty = tid >> 4;

    float acc[4][4] = {};

    for (int k0 = 0; k0 < 64; k0 += 16) {
        float4 a4 = *(const float4*)&nf[(size_t)(m0 + sr) * 64 + k0 + kc];
        As[kc + 0][sr] = a4.x; As[kc + 1][sr] = a4.y;
        As[kc + 2][sr] = a4.z; As[kc + 3][sr] = a4.w;
        float4 b4 = *(const float4*)&Bp[(size_t)sr * 384 + k0 + kc];
        Bs[kc + 0][sr] = b4.x; Bs[kc + 1][sr] = b4.y;
        Bs[kc + 2][sr] = b4.z; Bs[kc + 3][sr] = b4.w;
        __syncthreads();
        #pragma unroll
        for (int k = 0; k < 16; ++k) {
            float av[4], bv[4];
            *(float4*)av = *(const float4*)&As[k][ty * 4];
            *(float4*)bv = *(const float4*)&Bs[k][tx * 4];
            #pragma unroll
            for (int r = 0; r < 4; ++r)
                #pragma unroll
                for (int c = 0; c < 4; ++c)
                    acc[r][c] = fmaf(av[r], bv[c], acc[r][c]);
        }
        __syncthreads();
    }

    unsigned short* dst = isJ ? Ujh : Uih;
    #pragma unroll
    for (int r = 0; r < 4; ++r) {
        int gm = m0 + ty * 4 + r;
        int bidx = gm / 50;
        #pragma unroll
        for (int c = 0; c < 4; ++c) {
            int gl = nb + tx * 4 + c;
            float v = acc[r][c];
            if (!isJ) v += Abc[(size_t)bidx * 512 + gl];
            dst[(size_t)gm * 512 + gl] =
                __builtin_bit_cast(unsigned short, (_Float16)v);
        }
    }
}

// ---------------------------------------------------------------------------
// MFMA edge kernel v6: R5 geometry (best measured) + fp16 datapath.
//  512 thr = 8 waves (2 wr x 4 wc), wave tile 64x64, acc[4][4], K-step 32.
//  A (e1 fp16): XOR-swizzled LDS, double-buffered; built with v_pk_add_f16 +
//    v_pk_max_f16 (8 packed ops/8 elems vs ~30 for the old bf16 path).
//  B (E2t fp16): gll -> triple-buffered LDS, prefetch distance 2.
//  Counted barrier: s_waitcnt vmcnt(4) keeps this iter's 4 vmem ops
//  (2 gll B(ks+2) + 2 U(ks+2) loads) in flight across the barrier.
// ---------------------------------------------------------------------------
__global__ __launch_bounds__(512, 4) void edge_mfma(
    const unsigned short* __restrict__ Ui,   // [B,50,512] fp16 (incl. Abc+c1)
    const unsigned short* __restrict__ Uj,   // [B,50,512] fp16
    const unsigned short* __restrict__ E2t,  // [64 kc][256 g][8] fp16
    const float* __restrict__ c2,
    const float* __restrict__ E3,
    const float* __restrict__ c3p,
    float* __restrict__ outE)                // [B,2450]
{
    __shared__ unsigned short As[2][PTILE * 32];   // 16KB, swizzled
    __shared__ unsigned short Bs[3][8192];         // 48KB, linear chunk-major
    __shared__ float c2_s[256], e3_s[256];
    __shared__ int   ii_s[PTILE], jj_s[PTILE];
    __shared__ float red[PTILE][5];

    const int b   = blockIdx.y;
    const int p0  = blockIdx.x * PTILE;
    const int tid = threadIdx.x;
    const int lane = tid & 63;
    const int wid  = tid >> 6;
    const int wr = wid >> 2;     // 0..1
    const int wc = wid & 3;      // 0..3
    const int ln = lane & 15;
    const int hi = lane >> 4;

    if (tid < 256) { c2_s[tid] = c2[tid]; e3_s[tid] = E3[tid]; }
    if (tid < PTILE) {
        int p = p0 + tid;
        int i = 0, j = 0;
        if (p < NPAIR) {
            i = p / 49;
            int kk = p - i * 49;
            j = kk + (kk >= i ? 1 : 0);
        }
        ii_s[tid] = i;
        jj_s[tid] = j;
    }
    __syncthreads();

    const unsigned short* UiB = Ui + (size_t)b * MAXN * HIDDEN;
    const unsigned short* UjB = Uj + (size_t)b * MAXN * HIDDEN;

    // A staging role: (row, 16B chunk) of the 128x32 k-step tile
    const int srow = tid >> 2;
    const int sc   = tid & 3;
    const unsigned short* gUi = UiB + (size_t)ii_s[srow] * HIDDEN + sc * 8;
    const unsigned short* gUj = UjB + (size_t)jj_s[srow] * HIDDEN + sc * 8;
    const int swr = srow * 32 + ((sc ^ ((srow >> 1) & 3)) * 8);

    // A fragment read address (swizzled)
    const int arow = 64 * wr + ln;
    const int q    = hi ^ ((ln >> 1) & 3);
    const int ard  = arow * 32 + q * 8;

    // B: per-wave gll source / LDS fragment read address
    const unsigned short* gB  = E2t + (wid * 2) * 512 + lane * 8;
    const int bdst = (wid * 2) * 512;                 // shorts, uniform/wave
    const int brd  = hi * 2048 + (64 * wc + ln) * 8;  // + ni*128

    f32x4 acc[4][4] = {};

    // ---- prologue: A(0) build->LDS; gll B(0)->Bs[0], B(1)->Bs[1]; U(1) regs
    {
        f16x8 ui = *(const f16x8*)gUi;
        f16x8 uj = *(const f16x8*)gUj;
        *(u32x4*)&As[0][swr] = build_e1(ui, uj);
    }
    gll16(gB,        &Bs[0][bdst]);
    gll16(gB + 512,  &Bs[0][bdst + 512]);
    gll16(gB + 8192, &Bs[1][bdst]);
    gll16(gB + 8704, &Bs[1][bdst + 512]);
    f16x8 uiN = *(const f16x8*)(gUi + 32);
    f16x8 ujN = *(const f16x8*)(gUj + 32);
    // drain B(0) (oldest); keep B(1)+U(1) (4 newest) in flight
    asm volatile("s_waitcnt vmcnt(4) lgkmcnt(0)\n\ts_barrier" ::: "memory");

    #pragma unroll
    for (int ks = 0; ks < 16; ++ks) {
        const int ab = ks & 1;        // A buffer
        const int bb = ks % 3;        // B buffer
        // issue B(ks+2) -> Bs[(ks+2)%3] (that buffer was last read at ks-1)
        if (ks < 14) {
            const int bn = (ks + 2) % 3;
            const unsigned short* src = gB + (size_t)(ks + 2) * 8192;
            gll16(src,       &Bs[bn][bdst]);
            gll16(src + 512, &Bs[bn][bdst + 512]);
        }
        // build + store A(ks+1) (consumes U(ks+1) loaded at iter ks-1)
        if (ks < 15)
            *(u32x4*)&As[ab ^ 1][swr] = build_e1(uiN, ujN);
        // prefetch U(ks+2) registers
        if (ks < 14) {
            uiN = *(const f16x8*)(gUi + 32 * (ks + 2));
            ujN = *(const f16x8*)(gUj + 32 * (ks + 2));
        }

        f16x8 af[4], bf[4];
        #pragma unroll
        for (int mi = 0; mi < 4; ++mi)
            af[mi] = *(const f16x8*)&As[ab][ard + mi * 512];
        #pragma unroll
        for (int ni = 0; ni < 4; ++ni)
            bf[ni] = *(const f16x8*)&Bs[bb][brd + ni * 128];

        __builtin_amdgcn_s_setprio(1);
        #pragma unroll
        for (int ni = 0; ni < 4; ++ni)
            #pragma unroll
            for (int mi = 0; mi < 4; ++mi)
                acc[mi][ni] = __builtin_amdgcn_mfma_f32_16x16x32_f16(
                    af[mi], bf[ni], acc[mi][ni], 0, 0, 0);
        __builtin_amdgcn_s_setprio(0);

        // counted-vmcnt barrier: keep the 4 newest (B(ks+2)+U(ks+2)) in
        // flight; everything older (incl. B(ks+1)) must be complete.
        if (ks < 14) {
            asm volatile("s_waitcnt vmcnt(4) lgkmcnt(0)\n\ts_barrier" ::: "memory");
        } else if (ks == 14) {
            asm volatile("s_waitcnt vmcnt(0) lgkmcnt(0)\n\ts_barrier" ::: "memory");
        }
        // ks == 15: no barrier needed; epilogue uses only regs + `red`
    }

    // ---- epilogue: relu(+c2), dot E3, 16-lane shuffle reduce, cross-wave LDS
    const float c3v = c3p[0];
    #pragma unroll
    for (int mi = 0; mi < 4; ++mi) {
        #pragma unroll
        for (int r = 0; r < 4; ++r) {
            float part = 0.f;
            #pragma unroll
            for (int ni = 0; ni < 4; ++ni) {
                int g = 64 * wc + 16 * ni + ln;
                float v = fmaxf(acc[mi][ni][r] + c2_s[g], 0.f);
                part = fmaf(v, e3_s[g], part);
            }
            part += __shfl_xor(part, 1);
            part += __shfl_xor(part, 2);
            part += __shfl_xor(part, 4);
            part += __shfl_xor(part, 8);
            if (ln == 0) red[64 * wr + 16 * mi + 4 * hi + r][wc] = part;
        }
    }
    __syncthreads();

    if (tid < PTILE) {
        int p = p0 + tid;
        if (p < NPAIR) {
            float s = red[tid][0] + red[tid][1] + red[tid][2] + red[tid][3] + c3v;
            outE[(size_t)b * NPAIR + p] = sigmoidf_(s);
        }
    }
}

// ---------------------------------------------------------------------------
extern "C" void kernel_launch(void* const* d_in, const int* in_sizes, int n_in,
                              void* d_out, int out_size, void* d_ws, size_t ws_size,
                              hipStream_t stream)
{
    const float* z  = (const float*)d_in[0];
    const float* W1 = (const float*)d_in[1];
    const float* b1 = (const float*)d_in[2];
    const float* W2 = (const float*)d_in[3];
    const float* b2 = (const float*)d_in[4];
    const float* W3 = (const float*)d_in[5];
    const float* b3 = (const float*)d_in[6];
    const float* E1 = (const float*)d_in[7];
    const float* c1 = (const float*)d_in[8];
    const float* E2 = (const float*)d_in[9];
    const float* c2 = (const float*)d_in[10];
    const float* E3 = (const float*)d_in[11];
    const float* c3 = (const float*)d_in[12];

    float* out = (float*)d_out;
    float* ws  = (float*)d_ws;

    // workspace layout
    float* h1  = ws;                        // 128*512 f32
    float* h2  = h1 + 65536;                // 128*512 f32
    float* nf  = h2 + 65536;                // 128*3200 f32
    float* Abc = nf + 409600;               // 128*512 f32
    unsigned short* Uih = (unsigned short*)(Abc + 65536);   // 128*50*512 fp16
    unsigned short* Ujh = Uih + (size_t)BATCH * MAXN * 512; // 128*50*512 fp16
    unsigned short* E2t = Ujh + (size_t)BATCH * MAXN * 512; // 64*256*8 fp16

    dim3 blk(256);

    // h1, Abc, E2t
    prologue_a<<<dim3(48, 2), blk, 0, stream>>>(z, W1, b1, E1, c1, E2, E2t, h1, Abc);

    // h2 = relu(h1@W2^T+b2)   (32 blocks)
    gemm_nt32<1><<<dim3(8, 4), blk, 0, stream>>>(
        h1, HIDDEN, W2, HIDDEN, b2, h2, HIDDEN, nullptr, HIDDEN);

    // nf raw -> ws ; sigmoid(nf) -> out   (200 blocks)
    gemm_nt32<2><<<dim3(50, 4), blk, 0, stream>>>(
        h2, HIDDEN, W3, HIDDEN, b3, nf, 3200, out, HIDDEN);

    // Ui' = f16(nf@E1i^T + Abc) ; Uj = f16(nf@E1j^T)
    uiuj_gemm<<<dim3(16, 100), blk, 0, stream>>>(nf, E1, Abc, Uih, Ujh);

    // fused edge MLP with MFMA (fp16)
    edge_mfma<<<dim3(NTILES, BATCH), dim3(512), 0, stream>>>(
        Uih, Ujh, E2t, c2, E3, c3, out + BATCH * MAXN * NFD);
}